// Round 9
// baseline (445.258 us; speedup 1.0000x reference)
//
#include <hip/hip_runtime.h>
#include <hip/hip_bf16.h>
#include <cstdint>

typedef short bf16x8 __attribute__((ext_vector_type(8)));
typedef short bf16x4 __attribute__((ext_vector_type(4)));
typedef float f32x4  __attribute__((ext_vector_type(4)));
typedef float f32x16 __attribute__((ext_vector_type(16)));

#define NB 4
#define NH 16
#define NS 2048
#define ND 128

constexpr int QBLK  = 128;          // 4 waves x 32 q-rows
constexpr int KVBLK = 64;
constexpr int KSZ   = KVBLK * ND;   // 8192 bf16 (16 KB)
constexpr int VSZ   = 8 * 1040;     // 8320 bf16 (16.6 KB)

// K LDS: row-major [64][128] bf16, 16B-granule XOR swizzle: byte ^= (row&7)<<4.
// V LDS: 4k x 16d row-major subtiles: elem(k,d) = (d>>4)*1040 + (k>>2)*64 + (k&3)*16 + (d&15).
//   ds_read_b64_tr_b16, lane base = (g&1)*2080 + (g>>1)*256 + lr*8 bytes delivers
//   (step db,s at offset db*4160+s*512(+128)) V[k=s*16+8h+j][d=db*32+(l&31)] = PV B-frag.
//
// Occupancy design: 1024 blocks of 4 waves, single-buffered LDS (33.6 KB) ->
// 3 blocks/CU (VGPR-capped via __launch_bounds__(256,3)) = 12 waves/CU + backfill.
// qb map m[s]: cohorts {s,s+4,s+8,s+12} (co-resident under wgid+256k model) sum
// to equal work (34 tile-units); bh = wgid&63 keeps each head's blocks on one XCD.

__device__ __forceinline__ unsigned short f2bf(float x) {
  union { __hip_bfloat16 h; unsigned short u; } cv;
  cv.h = __float2bfloat16(x);
  return cv.u;
}

__device__ __forceinline__ bf16x8 pack8(float4 a, float4 b) {
  bf16x8 t;
  t[0] = (short)f2bf(a.x); t[1] = (short)f2bf(a.y);
  t[2] = (short)f2bf(a.z); t[3] = (short)f2bf(a.w);
  t[4] = (short)f2bf(b.x); t[5] = (short)f2bf(b.y);
  t[6] = (short)f2bf(b.z); t[7] = (short)f2bf(b.w);
  return t;
}

__device__ __forceinline__ uint32_t pkbf(float lo, float hi) {
  uint32_t r;
  asm("v_cvt_pk_bf16_f32 %0, %1, %2" : "=v"(r) : "v"(lo), "v"(hi));
  return r;
}

__global__ void __launch_bounds__(256, 3)
attn_fwd(const float* __restrict__ Q, const float* __restrict__ K,
         const float* __restrict__ V, float* __restrict__ Out)
{
  __shared__ __align__(16) unsigned short Ks[KSZ];
  __shared__ __align__(16) unsigned short Vs[VSZ];
  __shared__ float xS[4][32];          // per-warp alpha / inv-lsum bounce

  const int tid = threadIdx.x;
  const int w   = tid >> 6;
  const int l   = tid & 63;
  const int lq  = l & 31;     // q-col (QK^T) / d-col (PV)
  const int h   = l >> 5;
  const int lr  = l & 15;
  const int g   = l >> 4;

  const int wgid = blockIdx.x;
  const int bh   = wgid & 63;
  const int sidx = wgid >> 6;          // 0..15
  const int s2   = sidx & 3, sc = sidx >> 2;
  const int qb   = (sc == 0) ? (15 - 2 * s2)
                 : (sc == 1) ? (2 * s2)
                 : (sc == 2) ? (14 - 2 * s2)
                 :             (1 + 2 * s2);
  const int qb0  = qb * QBLK;
  const int qw   = qb0 + w * 32;
  const int qrow = qw + lq;

  const float* Qb = Q + (size_t)bh * NS * ND;
  const float* Kb = K + (size_t)bh * NS * ND;
  const float* Vb = V + (size_t)bh * NS * ND;
  float*       Ob = Out + (size_t)bh * NS * ND;

  const float qscale = 0.08838834764831844f * 1.44269504088896340736f;

  // ---- Q as B-operand fragments: lane holds Q[qw+lq][dsl*16 + h*8 + i]
  bf16x8 qf[8];
#pragma unroll
  for (int dsl = 0; dsl < 8; ++dsl) {
    const float* src = Qb + (size_t)qrow * ND + dsl * 16 + h * 8;
    float4 a = *(const float4*)src;
    float4 b = *(const float4*)(src + 4);
    a.x *= qscale; a.y *= qscale; a.z *= qscale; a.w *= qscale;
    b.x *= qscale; b.y *= qscale; b.z *= qscale; b.w *= qscale;
    qf[dsl] = pack8(a, b);
  }

  f32x16 of[4];
#pragma unroll
  for (int db = 0; db < 4; ++db)
#pragma unroll
    for (int e = 0; e < 16; ++e) of[db][e] = 0.f;
  float mrow = -1e30f, lsum = 0.f;

  // staging constants (256 threads: row = tid>>2, float cols fc..fc+31)
  const int srow = tid >> 2;
  const int fc   = (tid & 3) * 32;
  const int swz  = (srow & 7) << 4;
  int kofs[4], vofs[4];
#pragma unroll
  for (int cc = 0; cc < 4; ++cc) {
    kofs[cc] = srow * 256 + ((2 * fc + 16 * cc) ^ swz);                  // bytes
    vofs[cc] = ((fc + 8 * cc) >> 4) * 1040 + (srow >> 2) * 64 +
               (srow & 3) * 16 + ((8 * cc) & 8);                          // elems
  }
  const int kswz = (lq & 7) << 4;

  const int nkv = 2 * qb + 2;

  // ---- staging helper (single buffer): loads + convert + write
#define STAGE(KB)                                                           \
  {                                                                         \
    const float* kp = Kb + (size_t)((KB) + srow) * ND + fc;                 \
    const float* vp = Vb + (size_t)((KB) + srow) * ND + fc;                 \
    float4 q0 = *(const float4*)(kp + 0),  q1 = *(const float4*)(kp + 4);   \
    float4 q2 = *(const float4*)(kp + 8),  q3 = *(const float4*)(kp + 12);  \
    float4 q4 = *(const float4*)(kp + 16), q5 = *(const float4*)(kp + 20);  \
    float4 q6 = *(const float4*)(kp + 24), q7 = *(const float4*)(kp + 28);  \
    *(bf16x8*)((char*)&Ks[0] + kofs[0]) = pack8(q0, q1);                    \
    *(bf16x8*)((char*)&Ks[0] + kofs[1]) = pack8(q2, q3);                    \
    *(bf16x8*)((char*)&Ks[0] + kofs[2]) = pack8(q4, q5);                    \
    *(bf16x8*)((char*)&Ks[0] + kofs[3]) = pack8(q6, q7);                    \
    q0 = *(const float4*)(vp + 0);  q1 = *(const float4*)(vp + 4);          \
    q2 = *(const float4*)(vp + 8);  q3 = *(const float4*)(vp + 12);         \
    q4 = *(const float4*)(vp + 16); q5 = *(const float4*)(vp + 20);         \
    q6 = *(const float4*)(vp + 24); q7 = *(const float4*)(vp + 28);         \
    *(bf16x8*)&Vs[vofs[0]] = pack8(q0, q1);                                 \
    *(bf16x8*)&Vs[vofs[1]] = pack8(q2, q3);                                 \
    *(bf16x8*)&Vs[vofs[2]] = pack8(q4, q5);                                 \
    *(bf16x8*)&Vs[vofs[3]] = pack8(q6, q7);                                 \
  }

  STAGE(0);
  __syncthreads();

  for (int it = 0; it < nkv; ++it) {
    const int kbase = it * KVBLK;

    if (kbase <= qw + 31) {   // wave has unmasked keys in this tile
      // ---- S^T = K Q^T : q in lane dim, k in reg dim
      f32x16 st[2];
#pragma unroll
      for (int e = 0; e < 16; ++e) { st[0][e] = 0.f; st[1][e] = 0.f; }
#pragma unroll
      for (int sub = 0; sub < 2; ++sub)
#pragma unroll
        for (int dsl = 0; dsl < 8; ++dsl) {
          bf16x8 kf = *(const bf16x8*)((const char*)&Ks[0] +
                                       (sub * 32 + lq) * 256 +
                                       ((dsl * 32 + h * 16) ^ kswz));
          st[sub] = __builtin_amdgcn_mfma_f32_32x32x16_bf16(kf, qf[dsl], st[sub], 0, 0, 0);
        }

      // ---- causal mask (diagonal tiles only); k_local = (r&3)+8*(r>>2)+4h
      if (kbase + 63 > qw) {
        const int thr = qrow - kbase - 4 * h;
#pragma unroll
        for (int sub = 0; sub < 2; ++sub)
#pragma unroll
          for (int r = 0; r < 16; ++r) {
            const int kls = sub * 32 + (r & 3) + 8 * (r >> 2);
            st[sub][r] = (kls > thr) ? -1e30f : st[sub][r];
          }
      }

      // ---- row max: 8-partial tree
      float t8[8];
#pragma unroll
      for (int i = 0; i < 8; ++i) t8[i] = fmaxf(st[0][i], st[0][i + 8]);
#pragma unroll
      for (int i = 0; i < 8; ++i) t8[i] = fmaxf(t8[i], fmaxf(st[1][i], st[1][i + 8]));
      float vm = fmaxf(fmaxf(fmaxf(t8[0], t8[1]), fmaxf(t8[2], t8[3])),
                       fmaxf(fmaxf(t8[4], t8[5]), fmaxf(t8[6], t8[7])));
      vm = fmaxf(vm, __shfl_xor(vm, 32));

      // ---- T13 defer-max (P bounded by 2^8)
      const bool defer = __all(vm <= mrow + 8.f);
      if (!defer) {
        const float mnew  = fmaxf(mrow, vm);
        const float alpha = exp2f(mrow - mnew);
        mrow = mnew;
        lsum *= alpha;
        xS[w][lq] = alpha;                                  // redistribute q->reg dim
        asm volatile("s_waitcnt lgkmcnt(0)" ::: "memory");
        f32x4 a4[4];
#pragma unroll
        for (int t = 0; t < 4; ++t) a4[t] = *(const f32x4*)&xS[w][t * 8 + 4 * h];
#pragma unroll
        for (int db = 0; db < 4; ++db)
#pragma unroll
          for (int r = 0; r < 16; ++r) of[db][r] *= a4[r >> 2][r & 3];
      }

      // ---- exponentiate + 8-partial tree sum
#pragma unroll
      for (int sub = 0; sub < 2; ++sub)
#pragma unroll
        for (int r = 0; r < 16; ++r)
          st[sub][r] = exp2f(st[sub][r] - mrow);
      float s8[8];
#pragma unroll
      for (int i = 0; i < 8; ++i) s8[i] = st[0][i] + st[0][i + 8];
#pragma unroll
      for (int i = 0; i < 8; ++i) s8[i] += st[1][i] + st[1][i + 8];
      float ps = ((s8[0] + s8[1]) + (s8[2] + s8[3])) +
                 ((s8[4] + s8[5]) + (s8[6] + s8[7]));
      ps += __shfl_xor(ps, 32);
      lsum += ps;

      // ---- P -> A-fragments fully in-register (T12)
      bf16x8 pa[4];
#pragma unroll
      for (int sub = 0; sub < 2; ++sub) {
        uint32_t c0 = pkbf(st[sub][0],  st[sub][1]);
        uint32_t c1 = pkbf(st[sub][2],  st[sub][3]);
        uint32_t c2 = pkbf(st[sub][4],  st[sub][5]);
        uint32_t c3 = pkbf(st[sub][6],  st[sub][7]);
        uint32_t c4 = pkbf(st[sub][8],  st[sub][9]);
        uint32_t c5 = pkbf(st[sub][10], st[sub][11]);
        uint32_t c6 = pkbf(st[sub][12], st[sub][13]);
        uint32_t c7 = pkbf(st[sub][14], st[sub][15]);
        asm volatile("v_permlane32_swap_b32 %0, %1" : "+v"(c0), "+v"(c2));
        asm volatile("v_permlane32_swap_b32 %0, %1" : "+v"(c1), "+v"(c3));
        asm volatile("v_permlane32_swap_b32 %0, %1" : "+v"(c4), "+v"(c6));
        asm volatile("v_permlane32_swap_b32 %0, %1" : "+v"(c5), "+v"(c7));
        union { uint32_t u[4]; bf16x8 v; } f0, f1;
        f0.u[0] = c0; f0.u[1] = c1; f0.u[2] = c2; f0.u[3] = c3;
        f1.u[0] = c4; f1.u[1] = c5; f1.u[2] = c6; f1.u[3] = c7;
        pa[sub * 2 + 0] = f0.v;
        pa[sub * 2 + 1] = f1.v;
      }

      // ---- O += P V : pipelined tr-reads, counted lgkmcnt, db-fastest order
      asm volatile("s_waitcnt lgkmcnt(0)" ::: "memory");
      const uint32_t vb = (uint32_t)(uintptr_t)&Vs[0] +
                          (uint32_t)((g & 1) * 2080 + (g >> 1) * 256 + lr * 8);
      bf16x4 ta0, ta1, tb0, tb1;

#define TR2(P0, P1, DB, S)                                                     \
      asm volatile("ds_read_b64_tr_b16 %0, %2 offset:%c3\n\t"                  \
                   "ds_read_b64_tr_b16 %1, %2 offset:%c4"                      \
                   : "=v"(P0), "=v"(P1)                                        \
                   : "v"(vb), "i"((DB)*4160 + (S)*512), "i"((DB)*4160 + (S)*512 + 128));

#define PVS(DB, S, PX0, PX1, WAITN)                                            \
      asm volatile("s_waitcnt lgkmcnt(" #WAITN ")" ::: "memory");              \
      __builtin_amdgcn_sched_barrier(0);                                       \
      { union { struct { bf16x4 lo, hi; } p; bf16x8 v; } uu;                   \
        uu.p.lo = PX0; uu.p.hi = PX1;                                          \
        of[DB] = __builtin_amdgcn_mfma_f32_32x32x16_bf16(pa[S], uu.v, of[DB], 0, 0, 0); }

      TR2(ta0, ta1, 0, 0);
      TR2(tb0, tb1, 1, 0);
      __builtin_amdgcn_s_setprio(1);
      PVS(0, 0, ta0, ta1, 2); TR2(ta0, ta1, 2, 0);
      PVS(1, 0, tb0, tb1, 2); TR2(tb0, tb1, 3, 0);
      PVS(2, 0, ta0, ta1, 2); TR2(ta0, ta1, 0, 1);
      PVS(3, 0, tb0, tb1, 2); TR2(tb0, tb1, 1, 1);
      PVS(0, 1, ta0, ta1, 2); TR2(ta0, ta1, 2, 1);
      PVS(1, 1, tb0, tb1, 2); TR2(tb0, tb1, 3, 1);
      PVS(2, 1, ta0, ta1, 2); TR2(ta0, ta1, 0, 2);
      PVS(3, 1, tb0, tb1, 2); TR2(tb0, tb1, 1, 2);
      PVS(0, 2, ta0, ta1, 2); TR2(ta0, ta1, 2, 2);
      PVS(1, 2, tb0, tb1, 2); TR2(tb0, tb1, 3, 2);
      PVS(2, 2, ta0, ta1, 2); TR2(ta0, ta1, 0, 3);
      PVS(3, 2, tb0, tb1, 2); TR2(tb0, tb1, 1, 3);
      PVS(0, 3, ta0, ta1, 2); TR2(ta0, ta1, 2, 3);
      PVS(1, 3, tb0, tb1, 2); TR2(tb0, tb1, 3, 3);
      PVS(2, 3, ta0, ta1, 2);
      PVS(3, 3, tb0, tb1, 0);
      __builtin_amdgcn_s_setprio(0);
#undef TR2
#undef PVS
    }

    __syncthreads();                 // all reads of the buffer complete
    if (it + 1 < nkv) {
      STAGE(kbase + KVBLK);          // overwrite single buffer
    }
    __syncthreads();                 // staged tile visible
  }
#undef STAGE

  // ---- epilogue: redistribute 1/lsum (q lives in reg dim of `of`), store
  xS[w][lq] = 1.0f / lsum;
  asm volatile("s_waitcnt lgkmcnt(0)" ::: "memory");
  f32x4 inv4[4];
#pragma unroll
  for (int t = 0; t < 4; ++t) inv4[t] = *(const f32x4*)&xS[w][t * 8 + 4 * h];
#pragma unroll
  for (int t = 0; t < 4; ++t)
#pragma unroll
    for (int j = 0; j < 4; ++j) {
      const int qr = qw + t * 8 + 4 * h + j;
      const float iv = inv4[t][j];
#pragma unroll
      for (int db = 0; db < 4; ++db)
        Ob[(size_t)qr * ND + db * 32 + lq] = of[db][t * 4 + j] * iv;
    }
}

extern "C" void kernel_launch(void* const* d_in, const int* in_sizes, int n_in,
                              void* d_out, int out_size, void* d_ws, size_t ws_size,
                              hipStream_t stream) {
  const float* Q = (const float*)d_in[0];
  const float* K = (const float*)d_in[1];
  const float* V = (const float*)d_in[2];
  // d_in[3] is the causal mask; causality computed analytically (mask == tril by construction)
  float* O = (float*)d_out;

  attn_fwd<<<dim3((NS / QBLK) * NB * NH), dim3(256), 0, stream>>>(Q, K, V, O);
}